// Round 20
// baseline (39.540 us; speedup 1.0000x reference)
//
#include <hip/hip_runtime.h>

#define DEV static __device__ __forceinline__

// float4-preserving skewed LDS addressing: physical = j + 4*(j/128).
// 16B-aligned float4s stay contiguous (b128 ops); +4-float pad per 128 breaks
// power-of-2 bank aliasing. Max phys for T=4096: 4095 + 4*31 = 4219 < 4224.
#define SKEW4(j) ((j) + (((j) >> 7) << 2))

DEV float elem(const float4& v, int j) {
  switch (j & 3) {
    case 0: return v.x;
    case 1: return v.y;
    case 2: return v.z;
    default: return v.w;
  }
}
DEV void setelem(float4& v, int j, float x) {
  switch (j & 3) {
    case 0: v.x = x; break;
    case 1: v.y = x; break;
    case 2: v.z = x; break;
    default: v.w = x; break;
  }
}

// ---------------------------------------------------------------------------
// 2-wave, NO-stage-in kernel + post-scan obs prefetch (P == 12, T % 4 == 0,
// 12 <= T <= 4096).
//
// Round-19 winner (38.8 us) + one change: the out phase's obs reads are
// issued EARLY — right after the tot-exchange barrier — into O[8] registers,
// draining under the wave-start application + pass2 VALU work (T14 pattern).
// O is live only AFTER the scan, so it cannot trigger the scan-spill failure
// mode (rounds 7/10/15: +32 live regs across the scan -> scratch).
//
// err is NOT staged to LDS: each lane loads its window (E[9], 48B granules)
// DIRECTLY from global (read path — no write-allocate RMW; that hazard is
// writes-only, round 13). er_s is y-staging ONLY (pass2 writes cur b128;
// out phase combines O[k] + coalesced LDS reads). 2 barriers total.
//
// ETS state x = (level, trend, s[0..11]) evolves affinely; over whole periods
// the homogeneous map is the closed COMPRESSED family (HW-validated r10-19):
//   l -> l + GL*tr + sum_j (GA - Gf*j) s_j ; tr -> tr + Gf*sum_j s_j ;
//   s_j -> Gd*s_j   (+ particular Pl, Pt, Ps[12]).
// Per-wave 6-round Kogge-Stone scan (18 floats/round); wave-0 total crosses
// via LDS and wave 1 applies it to x0 as a STATE transform. E[9] at m<=3 is
// spill-free (rounds 13/19: VGPR 60). NO min-waves cap (round-7 lesson).
// ---------------------------------------------------------------------------
__global__ __launch_bounds__(128) void ets_w2p(
    const float* __restrict__ alpha_, const float* __restrict__ beta_,
    const float* __restrict__ gamma_, const float* __restrict__ lvl0,
    const float* __restrict__ tr0, const float* __restrict__ seas0,
    const float* __restrict__ obs, const float* __restrict__ err,
    float* __restrict__ out, int T)
{
  __shared__ __align__(16) float er_s[4224];  // y (cur) staging ONLY
  __shared__ float tot[20];                   // wave-0 inclusive map

  const int n = blockIdx.x;
  const int tid = threadIdx.x;
  const int lane = tid & 63;
  const int wv = tid >> 6;

  const float4* OB4 = reinterpret_cast<const float4*>(obs + (size_t)n * T);
  const int nf4 = T >> 2;

  const int nper = T / 12;
  const int base = nper >> 7, rem = nper & 127;
  const int m  = base + (tid < rem ? 1 : 0);     // periods this lane owns (<=3)
  const int p0 = tid * base + min(tid, rem);     // first period
  const int t0 = p0 * 12;

  // ---- E[9] window loaded DIRECTLY from global (issues immediately) -------
  const float* er = err + (size_t)n * T + (size_t)t0;
  float4 E[9];
#pragma unroll
  for (int u = 0; u < 3; ++u) {
    if (u < m) {
      const float4* e4 = reinterpret_cast<const float4*>(er + u * 12);
      E[u * 3 + 0] = e4[0];
      E[u * 3 + 1] = e4[1];
      E[u * 3 + 2] = e4[2];
    }
  }

  const float a = alpha_[n], b = beta_[n], g = gamma_[n];
  const float ab = a * b, ig = 1.0f - g;

  // ---- pass1: particular solution from zero state (register-only) ---------
  float l = 0.f, tr = 0.f, s[12];
#pragma unroll
  for (int j = 0; j < 12; ++j) s[j] = 0.f;
#pragma unroll
  for (int u = 0; u < 3; ++u) {
    if (u < m) {
#pragma unroll
      for (int j = 0; j < 12; ++j) {
        float e = elem(E[u * 3 + (j >> 2)], j);
        float se = s[j] + e;
        float lt = l + tr;
        l  = fmaf(a, se, lt);
        tr = fmaf(ab, se, tr);
        s[j] = fmaf(g, e, ig * s[j]);
      }
    }
  }

  // ---- analytic compressed homogeneous map for this lane's m periods ------
  float S0 = 0.f, S1 = 0.f, dk = 1.f;
  for (int k = 0; k < m; ++k) { S0 += dk; S1 += (float)k * dk; dk *= ig; }
  float GL = 12.0f * (float)m;                   // l += GL * tr
  float Gd = dk;                                 // s_j *= Gd (m==0 -> identity)
  float Gf = ab * S0;                            // tr += Gf * sum(s)
  float GA = fmaf(a, S0, ab * ((GL - 1.0f) * S0 - 12.0f * S1)); // c_j = GA-Gf*j
  float Pl = l, Pt = tr, Ps[12];
#pragma unroll
  for (int j = 0; j < 12; ++j) Ps[j] = s[j];

  // ---- per-wave Kogge-Stone inclusive scan (compressed maps, proven) ------
#pragma unroll
  for (int dlt = 1; dlt < 64; dlt <<= 1) {
    float oL  = __shfl_up(GL, dlt, 64);
    float od  = __shfl_up(Gd, dlt, 64);
    float of  = __shfl_up(Gf, dlt, 64);
    float oA  = __shfl_up(GA, dlt, 64);
    float oPl = __shfl_up(Pl, dlt, 64);
    float oPt = __shfl_up(Pt, dlt, 64);
    float oPs[12];
#pragma unroll
    for (int j = 0; j < 12; ++j) oPs[j] = __shfl_up(Ps[j], dlt, 64);
    if (lane >= dlt) {
      float S = 0.f, W = 0.f;
#pragma unroll
      for (int j = 0; j < 12; ++j) {
        S += oPs[j];
        W = fmaf((float)j, oPs[j], W);
      }
      float dot = GA * S - Gf * W;
      float nPl = oPl + GL * oPt + dot + Pl;
      float nPt = fmaf(Gf, S, oPt) + Pt;
#pragma unroll
      for (int j = 0; j < 12; ++j) Ps[j] = fmaf(Gd, oPs[j], Ps[j]);
      GA = oA + GL * of + GA * od;
      Pl = nPl; Pt = nPt;
      Gf = of + Gf * od;
      Gd = od * Gd;
      GL = oL + GL;
    }
  }

  // ---- exchange wave-0 total ----------------------------------------------
  if (wv == 0 && lane == 63) {
    tot[0] = GL; tot[1] = Gd; tot[2] = Gf; tot[3] = GA; tot[4] = Pl; tot[5] = Pt;
#pragma unroll
    for (int j = 0; j < 12; ++j) tot[6 + j] = Ps[j];
  }
  __syncthreads();

  // ---- EARLY obs prefetch: issues now, drains under pass2 (T14) -----------
  float4 O[8];
#pragma unroll
  for (int k = 0; k < 8; ++k) {
    int i = tid + (k << 7);
    if (i < nf4) O[k] = OB4[i];
  }

  // ---- wave-start state: x0 for wave 0; tot applied to x0 for wave 1 ------
  float xl = lvl0[n], xt = tr0[n], xs[12];
#pragma unroll
  for (int j = 0; j < 12; ++j) xs[j] = seas0[(size_t)n * 12 + j];
  if (wv == 1) {
    float ss = 0.f, sw = 0.f;
#pragma unroll
    for (int j = 0; j < 12; ++j) {
      ss += xs[j];
      sw = fmaf((float)j, xs[j], sw);
    }
    float cdot = tot[3] * ss - tot[2] * sw;
    float nxl = xl + tot[0] * xt + cdot + tot[4];
    float nxt = fmaf(tot[2], ss, xt) + tot[5];
#pragma unroll
    for (int j = 0; j < 12; ++j) xs[j] = fmaf(tot[1], xs[j], tot[6 + j]);
    xl = nxl; xt = nxt;
  }

  // ---- apply inclusive map to wave-start -> state AFTER this lane's chunk -
  float ss = 0.f, sw = 0.f;
#pragma unroll
  for (int j = 0; j < 12; ++j) {
    ss += xs[j];
    sw = fmaf((float)j, xs[j], sw);
  }
  float cdot = GA * ss - Gf * sw;
  float yl = xl + GL * xt + cdot + Pl;
  float yt = fmaf(Gf, ss, xt) + Pt;
  float ys[12];
#pragma unroll
  for (int j = 0; j < 12; ++j) ys[j] = fmaf(Gd, xs[j], Ps[j]);

  // exclusive shift: lane's true initial state = previous lane's inclusive;
  // lane 0 of each wave takes its wave-start state.
  l  = __shfl_up(yl, 1, 64);
  tr = __shfl_up(yt, 1, 64);
#pragma unroll
  for (int j = 0; j < 12; ++j) s[j] = __shfl_up(ys[j], 1, 64);
  if (lane == 0) {
    l = xl; tr = xt;
#pragma unroll
    for (int j = 0; j < 12; ++j) s[j] = xs[j];
  }

  // ---- pass2: cur from E + state -> er_s (b128) ---------------------------
#pragma unroll
  for (int u = 0; u < 3; ++u) {
    if (u < m) {
      float4 y0, y1, y2;
#pragma unroll
      for (int j = 0; j < 12; ++j) {
        float e = elem(E[u * 3 + (j >> 2)], j);
        float lt = l + tr;
        float cur = lt + s[j];
        float4& yd = (j < 4 ? y0 : (j < 8 ? y1 : y2));
        setelem(yd, j, cur);            // y minus the 0.1*obs term
        float se = s[j] + e;
        l  = fmaf(a, se, lt);
        tr = fmaf(ab, se, tr);
        s[j] = fmaf(g, e, ig * s[j]);
      }
      int t = t0 + u * 12;
      *reinterpret_cast<float4*>(&er_s[SKEW4(t)])     = y0;
      *reinterpret_cast<float4*>(&er_s[SKEW4(t + 4)]) = y1;
      *reinterpret_cast<float4*>(&er_s[SKEW4(t + 8)]) = y2;
    }
  }
  // tail (< 12 steps, slot phase 0): last thread continues; tail err comes
  // straight from global (never in E), cur goes into er_s for the out phase.
  if (tid == 127) {
    int tt = nper * 12;
    int tail = T - tt;
    if (tail > 0) {
      const float* et = err + (size_t)n * T + tt;
#pragma unroll
      for (int j = 0; j < 11; ++j) {
        if (j < tail) {
          float e = et[j];
          float lt = l + tr;
          float cur = lt + s[j];
          er_s[SKEW4(tt + j)] = cur;
          float se = s[j] + e;
          l  = fmaf(a, se, lt);
          tr = fmaf(ab, se, tr);
          s[j] = fmaf(g, e, ig * s[j]);
        }
      }
    }
  }

  __syncthreads();

  // ---- out: y = cur + 0.1*obs, prefetched obs + coalesced LDS reads -------
  float4* Y4 = reinterpret_cast<float4*>(out + (size_t)n * T);
#pragma unroll
  for (int k = 0; k < 8; ++k) {
    int i = tid + (k << 7);
    if (i < nf4) {
      float4 c = *reinterpret_cast<const float4*>(&er_s[SKEW4(i << 2)]);
      Y4[i] = make_float4(fmaf(O[k].x, 0.1f, c.x), fmaf(O[k].y, 0.1f, c.y),
                          fmaf(O[k].z, 0.1f, c.z), fmaf(O[k].w, 0.1f, c.w));
    }
  }
}

// ---------------------------------------------------------------------------
// Generic fallback (any P/T): one thread per series, seasonal state in LDS.
// ---------------------------------------------------------------------------
__global__ void ets_gen(
    const float* __restrict__ alpha_, const float* __restrict__ beta_,
    const float* __restrict__ gamma_, const float* __restrict__ lvl0,
    const float* __restrict__ tr0, const float* __restrict__ seas0,
    const float* __restrict__ obs, const float* __restrict__ err,
    float* __restrict__ out, int N, int T, int P)
{
  extern __shared__ float smem[];
  int n = blockIdx.x * blockDim.x + threadIdx.x;
  if (n >= N) return;
  float* s = smem + (size_t)threadIdx.x * P;
  for (int j = 0; j < P; ++j) s[j] = seas0[(size_t)n * P + j];

  float a = alpha_[n], b = beta_[n], g = gamma_[n];
  float ia = 1.0f - a, ib = 1.0f - b, ig = 1.0f - g;
  float level = lvl0[n], trend = tr0[n];

  const float* on = obs + (size_t)n * T;
  const float* er = err + (size_t)n * T;
  float*       yo = out + (size_t)n * T;

  int idx = 0;
  for (int t = 0; t < T; ++t) {
    float onj = on[t], ej = er[t];
    float sj  = s[idx];
    float cur = level + trend + sj;
    yo[t] = fmaf(onj, 0.1f, cur);
    float lt  = level + trend;
    float nl  = fmaf(a, cur + ej, ia * lt);
    float nt  = fmaf(b, nl - level, ib * trend);
    s[idx]    = fmaf(g, ej, ig * sj);
    level = nl; trend = nt;
    if (++idx == P) idx = 0;
  }
}

extern "C" void kernel_launch(void* const* d_in, const int* in_sizes, int n_in,
                              void* d_out, int out_size, void* d_ws, size_t ws_size,
                              hipStream_t stream) {
  (void)n_in; (void)out_size; (void)d_ws; (void)ws_size;
  const float* alpha = (const float*)d_in[0];
  const float* beta  = (const float*)d_in[1];
  const float* gamma = (const float*)d_in[2];
  const float* lvl0  = (const float*)d_in[3];
  const float* tr0   = (const float*)d_in[4];
  const float* seas0 = (const float*)d_in[5];
  const float* obs   = (const float*)d_in[6];
  const float* err   = (const float*)d_in[7];
  float* y = (float*)d_out;

  int N = in_sizes[0];
  int P = in_sizes[5] / N;
  int T = in_sizes[6] / N;

  if (P == 12 && (T % 4) == 0 && T >= 12 && T <= 4096) {
    ets_w2p<<<dim3(N), dim3(128), 0, stream>>>(
        alpha, beta, gamma, lvl0, tr0, seas0, obs, err, y, T);
  } else {
    int bs = 64;
    size_t sh = (size_t)bs * (size_t)P * sizeof(float);
    ets_gen<<<dim3((N + bs - 1) / bs), dim3(bs), sh, stream>>>(
        alpha, beta, gamma, lvl0, tr0, seas0, obs, err, y, N, T, P);
  }
}

// Round 21
// 38.696 us; speedup vs baseline: 1.0218x; 1.0218x over previous
//
#include <hip/hip_runtime.h>

#define DEV static __device__ __forceinline__

// float4-preserving skewed LDS addressing: physical = j + 4*(j/128).
// 16B-aligned float4s stay contiguous (b128 ops); +4-float pad per 128 breaks
// power-of-2 bank aliasing. Max phys for T=4096: 4095 + 4*31 = 4219 < 4224.
#define SKEW4(j) ((j) + (((j) >> 7) << 2))

DEV float elem(const float4& v, int j) {
  switch (j & 3) {
    case 0: return v.x;
    case 1: return v.y;
    case 2: return v.z;
    default: return v.w;
  }
}
DEV void setelem(float4& v, int j, float x) {
  switch (j & 3) {
    case 0: v.x = x; break;
    case 1: v.y = x; break;
    case 2: v.z = x; break;
    default: v.w = x; break;
  }
}

// ---------------------------------------------------------------------------
// 2-wave, NO-stage-in kernel (P == 12, T % 4 == 0, 12 <= T <= 4096).
// ROUND-19 OPTIMUM, reverted to after round-20's obs-prefetch regressed
// (O[8] cost 8 VGPR -> occupancy 31->23%, worth more than the hidden latency).
//
// err is NOT staged to LDS: each lane loads its window (E[9], 48B granules)
// DIRECTLY from global — read path, so no write-allocate RMW (that hazard is
// writes-only, round 13). er_s is y-staging ONLY (pass2 writes cur b128;
// out phase reads coalesced and fuses y = cur + 0.1*obs). 2 barriers total.
//
// ETS state x = (level, trend, s[0..11]) evolves affinely; over whole periods
// the homogeneous map is the closed COMPRESSED family (HW-validated r10-20):
//   l -> l + GL*tr + sum_j (GA - Gf*j) s_j ; tr -> tr + Gf*sum_j s_j ;
//   s_j -> Gd*s_j   (+ particular Pl, Pt, Ps[12]).
// Per-wave 6-round Kogge-Stone scan (18 floats/round); wave-0 total crosses
// via LDS and wave 1 applies it to x0 as a STATE transform. E[9] at m<=3 is
// spill-free (VGPR 60). NO min-waves cap (round-7 spill lesson).
// ---------------------------------------------------------------------------
__global__ __launch_bounds__(128) void ets_w2g(
    const float* __restrict__ alpha_, const float* __restrict__ beta_,
    const float* __restrict__ gamma_, const float* __restrict__ lvl0,
    const float* __restrict__ tr0, const float* __restrict__ seas0,
    const float* __restrict__ obs, const float* __restrict__ err,
    float* __restrict__ out, int T)
{
  __shared__ __align__(16) float er_s[4224];  // y (cur) staging ONLY
  __shared__ float tot[20];                   // wave-0 inclusive map

  const int n = blockIdx.x;
  const int tid = threadIdx.x;
  const int lane = tid & 63;
  const int wv = tid >> 6;

  const float4* OB4 = reinterpret_cast<const float4*>(obs + (size_t)n * T);
  const int nf4 = T >> 2;

  const int nper = T / 12;
  const int base = nper >> 7, rem = nper & 127;
  const int m  = base + (tid < rem ? 1 : 0);     // periods this lane owns (<=3)
  const int p0 = tid * base + min(tid, rem);     // first period
  const int t0 = p0 * 12;

  // ---- E[9] window loaded DIRECTLY from global (issues immediately) -------
  const float* er = err + (size_t)n * T + (size_t)t0;
  float4 E[9];
#pragma unroll
  for (int u = 0; u < 3; ++u) {
    if (u < m) {
      const float4* e4 = reinterpret_cast<const float4*>(er + u * 12);
      E[u * 3 + 0] = e4[0];
      E[u * 3 + 1] = e4[1];
      E[u * 3 + 2] = e4[2];
    }
  }

  const float a = alpha_[n], b = beta_[n], g = gamma_[n];
  const float ab = a * b, ig = 1.0f - g;

  // ---- pass1: particular solution from zero state (register-only) ---------
  float l = 0.f, tr = 0.f, s[12];
#pragma unroll
  for (int j = 0; j < 12; ++j) s[j] = 0.f;
#pragma unroll
  for (int u = 0; u < 3; ++u) {
    if (u < m) {
#pragma unroll
      for (int j = 0; j < 12; ++j) {
        float e = elem(E[u * 3 + (j >> 2)], j);
        float se = s[j] + e;
        float lt = l + tr;
        l  = fmaf(a, se, lt);
        tr = fmaf(ab, se, tr);
        s[j] = fmaf(g, e, ig * s[j]);
      }
    }
  }

  // ---- analytic compressed homogeneous map for this lane's m periods ------
  float S0 = 0.f, S1 = 0.f, dk = 1.f;
  for (int k = 0; k < m; ++k) { S0 += dk; S1 += (float)k * dk; dk *= ig; }
  float GL = 12.0f * (float)m;                   // l += GL * tr
  float Gd = dk;                                 // s_j *= Gd (m==0 -> identity)
  float Gf = ab * S0;                            // tr += Gf * sum(s)
  float GA = fmaf(a, S0, ab * ((GL - 1.0f) * S0 - 12.0f * S1)); // c_j = GA-Gf*j
  float Pl = l, Pt = tr, Ps[12];
#pragma unroll
  for (int j = 0; j < 12; ++j) Ps[j] = s[j];

  // ---- per-wave Kogge-Stone inclusive scan (compressed maps, proven) ------
#pragma unroll
  for (int dlt = 1; dlt < 64; dlt <<= 1) {
    float oL  = __shfl_up(GL, dlt, 64);
    float od  = __shfl_up(Gd, dlt, 64);
    float of  = __shfl_up(Gf, dlt, 64);
    float oA  = __shfl_up(GA, dlt, 64);
    float oPl = __shfl_up(Pl, dlt, 64);
    float oPt = __shfl_up(Pt, dlt, 64);
    float oPs[12];
#pragma unroll
    for (int j = 0; j < 12; ++j) oPs[j] = __shfl_up(Ps[j], dlt, 64);
    if (lane >= dlt) {
      float S = 0.f, W = 0.f;
#pragma unroll
      for (int j = 0; j < 12; ++j) {
        S += oPs[j];
        W = fmaf((float)j, oPs[j], W);
      }
      float dot = GA * S - Gf * W;
      float nPl = oPl + GL * oPt + dot + Pl;
      float nPt = fmaf(Gf, S, oPt) + Pt;
#pragma unroll
      for (int j = 0; j < 12; ++j) Ps[j] = fmaf(Gd, oPs[j], Ps[j]);
      GA = oA + GL * of + GA * od;
      Pl = nPl; Pt = nPt;
      Gf = of + Gf * od;
      Gd = od * Gd;
      GL = oL + GL;
    }
  }

  // ---- exchange wave-0 total ----------------------------------------------
  if (wv == 0 && lane == 63) {
    tot[0] = GL; tot[1] = Gd; tot[2] = Gf; tot[3] = GA; tot[4] = Pl; tot[5] = Pt;
#pragma unroll
    for (int j = 0; j < 12; ++j) tot[6 + j] = Ps[j];
  }
  __syncthreads();

  // ---- wave-start state: x0 for wave 0; tot applied to x0 for wave 1 ------
  float xl = lvl0[n], xt = tr0[n], xs[12];
#pragma unroll
  for (int j = 0; j < 12; ++j) xs[j] = seas0[(size_t)n * 12 + j];
  if (wv == 1) {
    float ss = 0.f, sw = 0.f;
#pragma unroll
    for (int j = 0; j < 12; ++j) {
      ss += xs[j];
      sw = fmaf((float)j, xs[j], sw);
    }
    float cdot = tot[3] * ss - tot[2] * sw;
    float nxl = xl + tot[0] * xt + cdot + tot[4];
    float nxt = fmaf(tot[2], ss, xt) + tot[5];
#pragma unroll
    for (int j = 0; j < 12; ++j) xs[j] = fmaf(tot[1], xs[j], tot[6 + j]);
    xl = nxl; xt = nxt;
  }

  // ---- apply inclusive map to wave-start -> state AFTER this lane's chunk -
  float ss = 0.f, sw = 0.f;
#pragma unroll
  for (int j = 0; j < 12; ++j) {
    ss += xs[j];
    sw = fmaf((float)j, xs[j], sw);
  }
  float cdot = GA * ss - Gf * sw;
  float yl = xl + GL * xt + cdot + Pl;
  float yt = fmaf(Gf, ss, xt) + Pt;
  float ys[12];
#pragma unroll
  for (int j = 0; j < 12; ++j) ys[j] = fmaf(Gd, xs[j], Ps[j]);

  // exclusive shift: lane's true initial state = previous lane's inclusive;
  // lane 0 of each wave takes its wave-start state.
  l  = __shfl_up(yl, 1, 64);
  tr = __shfl_up(yt, 1, 64);
#pragma unroll
  for (int j = 0; j < 12; ++j) s[j] = __shfl_up(ys[j], 1, 64);
  if (lane == 0) {
    l = xl; tr = xt;
#pragma unroll
    for (int j = 0; j < 12; ++j) s[j] = xs[j];
  }

  // ---- pass2: cur from E + state -> er_s (b128) ---------------------------
#pragma unroll
  for (int u = 0; u < 3; ++u) {
    if (u < m) {
      float4 y0, y1, y2;
#pragma unroll
      for (int j = 0; j < 12; ++j) {
        float e = elem(E[u * 3 + (j >> 2)], j);
        float lt = l + tr;
        float cur = lt + s[j];
        float4& yd = (j < 4 ? y0 : (j < 8 ? y1 : y2));
        setelem(yd, j, cur);            // y minus the 0.1*obs term
        float se = s[j] + e;
        l  = fmaf(a, se, lt);
        tr = fmaf(ab, se, tr);
        s[j] = fmaf(g, e, ig * s[j]);
      }
      int t = t0 + u * 12;
      *reinterpret_cast<float4*>(&er_s[SKEW4(t)])     = y0;
      *reinterpret_cast<float4*>(&er_s[SKEW4(t + 4)]) = y1;
      *reinterpret_cast<float4*>(&er_s[SKEW4(t + 8)]) = y2;
    }
  }
  // tail (< 12 steps, slot phase 0): last thread continues; tail err comes
  // straight from global (never in E), cur goes into er_s for the out phase.
  if (tid == 127) {
    int tt = nper * 12;
    int tail = T - tt;
    if (tail > 0) {
      const float* et = err + (size_t)n * T + tt;
#pragma unroll
      for (int j = 0; j < 11; ++j) {
        if (j < tail) {
          float e = et[j];
          float lt = l + tr;
          float cur = lt + s[j];
          er_s[SKEW4(tt + j)] = cur;
          float se = s[j] + e;
          l  = fmaf(a, se, lt);
          tr = fmaf(ab, se, tr);
          s[j] = fmaf(g, e, ig * s[j]);
        }
      }
    }
  }

  __syncthreads();

  // ---- out: y = cur + 0.1*obs, coalesced ----------------------------------
  float4* Y4 = reinterpret_cast<float4*>(out + (size_t)n * T);
  for (int i = tid; i < nf4; i += 128) {
    float4 o = OB4[i];
    float4 c = *reinterpret_cast<const float4*>(&er_s[SKEW4(i << 2)]);
    Y4[i] = make_float4(fmaf(o.x, 0.1f, c.x), fmaf(o.y, 0.1f, c.y),
                        fmaf(o.z, 0.1f, c.z), fmaf(o.w, 0.1f, c.w));
  }
}

// ---------------------------------------------------------------------------
// Generic fallback (any P/T): one thread per series, seasonal state in LDS.
// ---------------------------------------------------------------------------
__global__ void ets_gen(
    const float* __restrict__ alpha_, const float* __restrict__ beta_,
    const float* __restrict__ gamma_, const float* __restrict__ lvl0,
    const float* __restrict__ tr0, const float* __restrict__ seas0,
    const float* __restrict__ obs, const float* __restrict__ err,
    float* __restrict__ out, int N, int T, int P)
{
  extern __shared__ float smem[];
  int n = blockIdx.x * blockDim.x + threadIdx.x;
  if (n >= N) return;
  float* s = smem + (size_t)threadIdx.x * P;
  for (int j = 0; j < P; ++j) s[j] = seas0[(size_t)n * P + j];

  float a = alpha_[n], b = beta_[n], g = gamma_[n];
  float ia = 1.0f - a, ib = 1.0f - b, ig = 1.0f - g;
  float level = lvl0[n], trend = tr0[n];

  const float* on = obs + (size_t)n * T;
  const float* er = err + (size_t)n * T;
  float*       yo = out + (size_t)n * T;

  int idx = 0;
  for (int t = 0; t < T; ++t) {
    float onj = on[t], ej = er[t];
    float sj  = s[idx];
    float cur = level + trend + sj;
    yo[t] = fmaf(onj, 0.1f, cur);
    float lt  = level + trend;
    float nl  = fmaf(a, cur + ej, ia * lt);
    float nt  = fmaf(b, nl - level, ib * trend);
    s[idx]    = fmaf(g, ej, ig * sj);
    level = nl; trend = nt;
    if (++idx == P) idx = 0;
  }
}

extern "C" void kernel_launch(void* const* d_in, const int* in_sizes, int n_in,
                              void* d_out, int out_size, void* d_ws, size_t ws_size,
                              hipStream_t stream) {
  (void)n_in; (void)out_size; (void)d_ws; (void)ws_size;
  const float* alpha = (const float*)d_in[0];
  const float* beta  = (const float*)d_in[1];
  const float* gamma = (const float*)d_in[2];
  const float* lvl0  = (const float*)d_in[3];
  const float* tr0   = (const float*)d_in[4];
  const float* seas0 = (const float*)d_in[5];
  const float* obs   = (const float*)d_in[6];
  const float* err   = (const float*)d_in[7];
  float* y = (float*)d_out;

  int N = in_sizes[0];
  int P = in_sizes[5] / N;
  int T = in_sizes[6] / N;

  if (P == 12 && (T % 4) == 0 && T >= 12 && T <= 4096) {
    ets_w2g<<<dim3(N), dim3(128), 0, stream>>>(
        alpha, beta, gamma, lvl0, tr0, seas0, obs, err, y, T);
  } else {
    int bs = 64;
    size_t sh = (size_t)bs * (size_t)P * sizeof(float);
    ets_gen<<<dim3((N + bs - 1) / bs), dim3(bs), sh, stream>>>(
        alpha, beta, gamma, lvl0, tr0, seas0, obs, err, y, N, T, P);
  }
}